// Round 10
// baseline (113.555 us; speedup 1.0000x reference)
//
#include <hip/hip_runtime.h>
#include <math.h>

#define N_PROP 1000
#define N_CLS  81
#define N_FG   80
#define SCORE_THRESH 0.05f
#define NMS_THRESH   0.5f
#define DET_PER_IMG  100
#define BBOX_CLIP    4.135166556742356f   // ln(1000/16)

// d_out layout (560000 floats):
//   [0, 400000)        out5: (80*1000, 5)
//   [400000, 480000)   labels as float
//   [480000, 560000)   final mask as 0.0/1.0
#define LBL_OFF    400000
#define FIN_OFF    480000

// histogram mapping: scores in (0.05, 1.0] -> u = bits in (0x3D4CCCCC, 0x3F800000]
// bin_abs = u >> 13 in (0x1EA66, 0x1FC00];  NB = 0x1FC00 - 0x1EA66 + 1 = 4507
#define BIN_LO 0x1EA66
#define NB     4507

// ws layout (bytes):
//   [0,4)               int   survivor count
//   [4,8)               int   done counter
//   [64, 320064)        float probT[80][1000]
//   [320064, 640064)    float compact survivor scores
//   [640064, 960064)    int   survivor row ids

// ---------------- K1: zero output + softmax -> probT (R4-proven) ----------
__global__ __launch_bounds__(256)
void softmax_zero_kernel(const float* __restrict__ logits,
                         float* __restrict__ out,
                         int* __restrict__ count,
                         int* __restrict__ done,
                         float* __restrict__ probT) {
    const int b = blockIdx.x;
    const int t = threadIdx.x;
    const int lane = t & 63;
    const int wave = t >> 6;
    if (b == 0 && t == 0) { *count = 0; *done = 0; }

    float4 z = make_float4(0.f, 0.f, 0.f, 0.f);
    float4* o4 = (float4*)out;
    for (int i = b * 256 + t; i < 140000; i += 250 * 256) o4[i] = z;

    const int n = b * 4 + wave;           // 250 blocks * 4 waves = 1000
    if (n < N_PROP) {
        const float* lrow = logits + (size_t)n * N_CLS;
        float v0 = lrow[lane];
        float v1 = (lane + 64 < N_CLS) ? lrow[lane + 64] : -INFINITY;
        float m = fmaxf(v0, v1);
        for (int off = 32; off; off >>= 1) m = fmaxf(m, __shfl_down(m, off));
        m = __shfl(m, 0);
        float e0 = expf(v0 - m);
        float e1 = (lane + 64 < N_CLS) ? expf(v1 - m) : 0.0f;
        float s = e0 + e1;
        for (int off = 32; off; off >>= 1) s += __shfl_down(s, off);
        s = __shfl(s, 0);
        if (lane >= 1)          probT[(size_t)(lane - 1) * N_PROP + n] = e0 / s;
        if (lane + 64 < N_CLS)  probT[(size_t)(lane + 63) * N_PROP + n] = e1 / s;
    }
}

__device__ __forceinline__ void decode_box(const float* __restrict__ props,
                                           const float* __restrict__ reg,
                                           int j, int cls, float W1, float H1,
                                           float& bx1, float& by1, float& bx2,
                                           float& by2, float& area) {
    float4 pr = *(const float4*)(props + (size_t)j * 4);
    float w  = pr.z - pr.x + 1.0f;
    float h  = pr.w - pr.y + 1.0f;
    float cx = pr.x + 0.5f * w;
    float cy = pr.y + 0.5f * h;
    float4 rr = *(const float4*)(reg + ((size_t)j * N_CLS + cls) * 4);
    float dx = rr.x / 10.0f;
    float dy = rr.y / 10.0f;
    float dw = fminf(rr.z / 5.0f, BBOX_CLIP);
    float dh = fminf(rr.w / 5.0f, BBOX_CLIP);
    float pcx = dx * w + cx;
    float pcy = dy * h + cy;
    float pw = expf(dw) * w;
    float ph = expf(dh) * h;
    bx1 = fminf(fmaxf(pcx - 0.5f * pw, 0.0f), W1);
    by1 = fminf(fmaxf(pcy - 0.5f * ph, 0.0f), H1);
    bx2 = fminf(fmaxf(pcx + 0.5f * pw - 1.0f, 0.0f), W1);
    by2 = fminf(fmaxf(pcy + 0.5f * ph - 1.0f, 0.0f), H1);
    area = (bx2 - bx1 + 1.0f) * (by2 - by1 + 1.0f);
}

// -------- K2: per-class NMS (register greedy) + last-block finalize --------
__global__ __launch_bounds__(256)
void nms_kernel(const float* __restrict__ probT,
                const float* __restrict__ props,
                const float* __restrict__ reg,
                const int* __restrict__ ihp,
                const int* __restrict__ iwp,
                float* __restrict__ out,
                int* __restrict__ count,
                int* __restrict__ done,
                float* __restrict__ compact,
                int* __restrict__ svRow) {
    const int c = blockIdx.x;       // 0..79
    const int t = threadIdx.x;      // 0..255
    const int lane = t & 63;
    const int wave = t >> 6;
    const int cls = c + 1;
    const unsigned long long lm = (1ull << lane) - 1ull;

    __shared__ float sSc[N_PROP];
    __shared__ int   sIdx[N_PROP];
    __shared__ float sx1[128], sy1[128], sx2[128], sy2[128], sar[128], sSc2[128];
    __shared__ int   sJdx[128];
    __shared__ float lsc[8192];     // finalize staging / V>128 fallback carve
    __shared__ int   hist[NB];
    __shared__ int   shV;
    __shared__ int   sBinAbs;
    __shared__ float sTh;
    __shared__ int   red4[4];

    const float W1 = (float)iwp[0] - 1.0f;
    const float H1 = (float)ihp[0] - 1.0f;

    // ---- phase 0: coalesced score load ----
    for (int j = t; j < N_PROP; j += 256) sSc[j] = probT[(size_t)c * N_PROP + j];
    __syncthreads();

    // ---- phase 1: wave-0 ballot compaction (R6-proven, in-place safe) ----
    if (t < 64) {
        int Vl = 0;
        #pragma unroll
        for (int it = 0; it < 16; ++it) {
            int j = it * 64 + lane;
            float sc = (j < N_PROP) ? sSc[j] : -1.0f;
            bool val = (j < N_PROP) && (sc > SCORE_THRESH);
            unsigned long long mask = __ballot(val);
            if (val) { int p = Vl + __popcll(mask & lm); sSc[p] = sc; sIdx[p] = j; }
            Vl += __popcll(mask);
        }
        if (lane == 0) shV = Vl;
    }
    __syncthreads();
    const int V = shV;

    if (V <= 128) {
        // ---- phase 2: rank + decode, thread t owns compacted entry t ----
        if (t < V) {
            float s = sSc[t];
            int id = sIdx[t];
            int r = 0;
            for (int u = 0; u < V; ++u) {
                float su = sSc[u];
                r += (su > s) || (su == s && sIdx[u] < id);
            }
            float bx1, by1, bx2, by2, ar;
            decode_box(props, reg, id, cls, W1, H1, bx1, by1, bx2, by2, ar);
            sx1[r] = bx1; sy1[r] = by1; sx2[r] = bx2; sy2[r] = by2;
            sar[r] = ar; sSc2[r] = s; sJdx[r] = id;
        }
        __syncthreads();

        // ---- phase 3: wave 0 — column masks in registers + ballot greedy ----
        if (wave == 0) {
            float ax1 = 0.f, ay1 = 0.f, ax2 = 0.f, ay2 = 0.f, aA = 0.f;
            float bx1 = 0.f, by1 = 0.f, bx2 = 0.f, by2 = 0.f, bA = 0.f;
            const bool hasA = (lane < V), hasB = (64 + lane < V);
            if (hasA) { ax1 = sx1[lane]; ay1 = sy1[lane]; ax2 = sx2[lane]; ay2 = sy2[lane]; aA = sar[lane]; }
            if (hasB) { bx1 = sx1[64 + lane]; by1 = sy1[64 + lane]; bx2 = sx2[64 + lane]; by2 = sy2[64 + lane]; bA = sar[64 + lane]; }

            unsigned long long Mlo = 0ull, M2lo = 0ull, M2hi = 0ull;
            for (int r = 0; r < V; ++r) {
                float rx1 = sx1[r], ry1 = sy1[r], rx2 = sx2[r], ry2 = sy2[r], rA = sar[r];
                if (hasA && r < lane) {
                    float iw = fmaxf(fminf(rx2, ax2) - fmaxf(rx1, ax1) + 1.0f, 0.0f);
                    float ih = fmaxf(fminf(ry2, ay2) - fmaxf(ry1, ay1) + 1.0f, 0.0f);
                    float inter = iw * ih;
                    float iou = inter / (rA + aA - inter);
                    if (iou > NMS_THRESH) Mlo |= 1ull << r;        // NaN-safe
                }
                if (hasB && r < 64 + lane) {
                    float iw = fmaxf(fminf(rx2, bx2) - fmaxf(rx1, bx1) + 1.0f, 0.0f);
                    float ih = fmaxf(fminf(ry2, by2) - fmaxf(ry1, by1) + 1.0f, 0.0f);
                    float inter = iw * ih;
                    float iou = inter / (rA + bA - inter);
                    if (iou > NMS_THRESH) {
                        if (r < 64) M2lo |= 1ull << r; else M2hi |= 1ull << (r - 64);
                    }
                }
            }

            // greedy scan: pure ballot/bit ops (no LDS in the loop)
            unsigned long long keep = 0ull, keep2 = 0ull;
            bool a = hasA, a2 = hasB;   // undecided flags
            while (true) {
                unsigned long long b1 = __ballot(a);
                unsigned long long b2 = __ballot(a2);
                if (!(b1 | b2)) break;
                int r = b1 ? (__ffsll((long long)b1) - 1) : (64 + __ffsll((long long)b2) - 1);
                if (r < 64) {
                    keep |= 1ull << r;
                    if (a  && ((Mlo  >> r) & 1ull)) a  = false;
                    if (a2 && ((M2lo >> r) & 1ull)) a2 = false;
                    if (lane == r) a = false;
                } else {
                    int rr = r - 64;
                    keep2 |= 1ull << rr;
                    if (a2 && ((M2hi >> rr) & 1ull)) a2 = false;
                    if (lane == rr) a2 = false;
                }
            }

            // wave-aggregated survivor append + output writes
            int total = __popcll(keep) + __popcll(keep2);
            int base = 0;
            if (lane == 0 && total > 0) base = atomicAdd(count, total);
            base = __shfl(base, 0);
            if ((keep >> lane) & 1ull) {
                float sc = sSc2[lane];
                int row = c * N_PROP + sJdx[lane];
                size_t o = (size_t)row * 5;
                out[o + 0] = ax1; out[o + 1] = ay1; out[o + 2] = ax2; out[o + 3] = ay2;
                out[o + 4] = sc;
                out[LBL_OFF + row] = (float)cls;
                out[FIN_OFF + row] = 1.0f;
                int pos = base + __popcll(keep & lm);
                compact[pos] = sc; svRow[pos] = row;
            }
            if ((keep2 >> lane) & 1ull) {
                float sc = sSc2[64 + lane];
                int row = c * N_PROP + sJdx[64 + lane];
                size_t o = (size_t)row * 5;
                out[o + 0] = bx1; out[o + 1] = by1; out[o + 2] = bx2; out[o + 3] = by2;
                out[o + 4] = sc;
                out[LBL_OFF + row] = (float)cls;
                out[FIN_OFF + row] = 1.0f;
                int pos = base + __popcll(keep) + __popcll(keep2 & lm);
                compact[pos] = sc; svRow[pos] = row;
            }
        }
    } else {
        // ---- fallback V > 128: proven 256-thread sequential path ----
        float* fx1 = lsc;          float* fy1 = lsc + 1000;
        float* fx2 = lsc + 2000;   float* fy2 = lsc + 3000;
        float* fa  = lsc + 4000;   float* fs  = lsc + 5000;
        int*   fj  = (int*)(lsc + 6000);
        int*   fk  = (int*)(lsc + 7000);
        for (int v = t; v < V; v += 256) {
            float s = sSc[v];
            int id = sIdx[v];
            int r = 0;
            for (int u = 0; u < V; ++u) {
                float su = sSc[u];
                r += (su > s) || (su == s && sIdx[u] < id);
            }
            float bx1, by1, bx2, by2, ar;
            decode_box(props, reg, id, cls, W1, H1, bx1, by1, bx2, by2, ar);
            fx1[r] = bx1; fy1[r] = by1; fx2[r] = bx2; fy2[r] = by2;
            fa[r] = ar; fs[r] = s; fj[r] = id; fk[r] = 1;
        }
        __syncthreads();
        for (int r = 0; r < V; ++r) {
            if (fk[r]) {
                const float X1 = fx1[r], Y1 = fy1[r], X2 = fx2[r], Y2 = fy2[r], A = fa[r];
                for (int v = r + 1 + t; v < V; v += 256) {
                    if (fk[v]) {
                        float iw = fmaxf(fminf(X2, fx2[v]) - fmaxf(X1, fx1[v]) + 1.0f, 0.0f);
                        float ih = fmaxf(fminf(Y2, fy2[v]) - fmaxf(Y1, fy1[v]) + 1.0f, 0.0f);
                        float inter = iw * ih;
                        float iou = inter / (A + fa[v] - inter);
                        if (iou > NMS_THRESH) fk[v] = 0;
                    }
                }
            }
            __syncthreads();
        }
        for (int v = t; v < V; v += 256) {
            if (fk[v]) {
                int row = c * N_PROP + fj[v];
                size_t o = (size_t)row * 5;
                out[o + 0] = fx1[v]; out[o + 1] = fy1[v];
                out[o + 2] = fx2[v]; out[o + 3] = fy2[v];
                out[o + 4] = fs[v];
                out[LBL_OFF + row] = (float)cls;
                out[FIN_OFF + row] = 1.0f;
                int pos = atomicAdd(count, 1);
                compact[pos] = fs[v]; svRow[pos] = row;
            }
        }
    }
    __syncthreads();

    // ---- last-block finalize (R6/R9-proven pattern) ----
    __threadfence();
    if (t == 0) {
        int old = __hip_atomic_fetch_add(done, 1, __ATOMIC_ACQ_REL, __HIP_MEMORY_SCOPE_AGENT);
        shV = (old == N_FG - 1) ? 1 : 0;   // reuse shV as "am I last"
    }
    __syncthreads();
    if (!shV) return;
    __threadfence();

    const int n = __hip_atomic_load(count, __ATOMIC_RELAXED, __HIP_MEMORY_SCOPE_AGENT);
    if (n <= DET_PER_IMG) return;   // th = 0 -> all survivors pass

    const bool useL = (n <= 8192);
    float th;
    if (useL) {
        // stage scores + build histogram
        for (int i = t; i < NB; i += 256) hist[i] = 0;
        __syncthreads();
        for (int i = t; i < n; i += 256) {
            float v = __hip_atomic_load(&compact[i], __ATOMIC_RELAXED, __HIP_MEMORY_SCOPE_AGENT);
            lsc[i] = v;
            atomicAdd(&hist[(int)(__float_as_uint(v) >> 13) - BIN_LO], 1);
        }
        __syncthreads();

        // wave 0: find the value-bin containing the 101st largest (suffix scan)
        if (wave == 0) {
            const int R = 71;                         // 64*71 >= NB
            int base = lane * R;
            int lim = (base + R < NB) ? base + R : NB;
            int partial = 0;
            for (int rb = base; rb < lim; ++rb) partial += hist[NB - 1 - rb];
            int x = partial;
            for (int off = 1; off < 64; off <<= 1) {
                int y = __shfl_up(x, off);
                if (lane >= off) x += y;
            }
            int cum = x - partial;                    // exclusive prefix (higher-value bins)
            for (int rb = base; rb < lim; ++rb) {
                int cc = hist[NB - 1 - rb];
                if (cum < DET_PER_IMG + 1 && cum + cc >= DET_PER_IMG + 1)
                    sBinAbs = (NB - 1 - rb) + BIN_LO;
                cum += cc;
            }
        }
        __syncthreads();
        const int binAbs = sBinAbs;

        // exact rank among all survivors, candidates limited to the bin
        for (int i = t; i < n; i += 256) {
            float v = lsc[i];
            if ((int)(__float_as_uint(v) >> 13) == binAbs) {
                int g = 0, e = 0;
                for (int k = 0; k < n; ++k) {
                    float w = lsc[k];
                    g += (w > v); e += (w == v);
                }
                if (g < DET_PER_IMG + 1 && DET_PER_IMG + 1 <= g + e) sTh = v;
            }
        }
        __syncthreads();
        th = sTh;
    } else {
        // cold fallback (n > 8192): proven bit binary search on global
        unsigned lo = 0x3D4CCCCCu, hi = 0x40000000u;
        while (hi - lo > 1u) {
            unsigned mid = lo + ((hi - lo) >> 1);
            float mv = __uint_as_float(mid);
            int cnt = 0;
            for (int i = t; i < n; i += 256)
                cnt += (__hip_atomic_load(&compact[i], __ATOMIC_RELAXED, __HIP_MEMORY_SCOPE_AGENT) >= mv) ? 1 : 0;
            for (int off = 32; off; off >>= 1) cnt += __shfl_down(cnt, off);
            if (lane == 0) red4[wave] = cnt;
            __syncthreads();
            int total = red4[0] + red4[1] + red4[2] + red4[3];
            __syncthreads();
            if (total >= DET_PER_IMG + 1) lo = mid; else hi = mid;
        }
        th = __uint_as_float(lo);
    }

    // fixup: zero rows whose score fails the image threshold
    for (int i = t; i < n; i += 256) {
        float sc = useL ? lsc[i]
                        : __hip_atomic_load(&compact[i], __ATOMIC_RELAXED, __HIP_MEMORY_SCOPE_AGENT);
        if (sc < th) {
            int row = __hip_atomic_load(&svRow[i], __ATOMIC_RELAXED, __HIP_MEMORY_SCOPE_AGENT);
            size_t o = (size_t)row * 5;
            out[o + 0] = 0.0f; out[o + 1] = 0.0f; out[o + 2] = 0.0f;
            out[o + 3] = 0.0f; out[o + 4] = 0.0f;
            out[LBL_OFF + row] = 0.0f;
            out[FIN_OFF + row] = 0.0f;
        }
    }
}

extern "C" void kernel_launch(void* const* d_in, const int* in_sizes, int n_in,
                              void* d_out, int out_size, void* d_ws, size_t ws_size,
                              hipStream_t stream) {
    const float* logits = (const float*)d_in[0];
    const float* reg    = (const float*)d_in[1];
    const float* props  = (const float*)d_in[2];
    const int*   ihp    = (const int*)d_in[3];
    const int*   iwp    = (const int*)d_in[4];
    float* out = (float*)d_out;

    char* ws = (char*)d_ws;
    int*   count   = (int*)(ws + 0);
    int*   done    = (int*)(ws + 4);
    float* probT   = (float*)(ws + 64);
    float* compact = (float*)(ws + 320064);
    int*   svRow   = (int*)(ws + 640064);

    softmax_zero_kernel<<<250, 256, 0, stream>>>(logits, out, count, done, probT);
    nms_kernel<<<N_FG, 256, 0, stream>>>(probT, props, reg, ihp, iwp,
                                         out, count, done, compact, svRow);
}

// Round 11
// 70.277 us; speedup vs baseline: 1.6158x; 1.6158x over previous
//
#include <hip/hip_runtime.h>
#include <math.h>

#define N_PROP 1000
#define N_CLS  81
#define N_FG   80
#define SCORE_THRESH 0.05f
#define NMS_THRESH   0.5f
#define DET_PER_IMG  100
#define BBOX_CLIP    4.135166556742356f   // ln(1000/16)

// d_out layout (560000 floats):
//   [0, 400000)        out5: (80*1000, 5)
//   [400000, 480000)   labels as float
//   [480000, 560000)   final mask as 0.0/1.0
#define LBL_OFF    400000
#define FIN_OFF    480000

// ws layout (bytes):
//   [0,4)               int   survivor count
//   [64, 320064)        float probT[80][1000]
//   [320064, 640064)    float compact survivor scores
//   [640064, 960064)    int   survivor row ids (c*1000+j)

// ---------------- K1: zero output + softmax -> probT (R4-proven) ----------
__global__ __launch_bounds__(256)
void softmax_zero_kernel(const float* __restrict__ logits,
                         float* __restrict__ out,
                         int* __restrict__ count,
                         float* __restrict__ probT) {
    const int b = blockIdx.x;
    const int t = threadIdx.x;
    const int lane = t & 63;
    const int wave = t >> 6;
    if (b == 0 && t == 0) *count = 0;

    float4 z = make_float4(0.f, 0.f, 0.f, 0.f);
    float4* o4 = (float4*)out;
    for (int i = b * 256 + t; i < 140000; i += 250 * 256) o4[i] = z;

    const int n = b * 4 + wave;           // 250 blocks * 4 waves = 1000
    if (n < N_PROP) {
        const float* lrow = logits + (size_t)n * N_CLS;
        float v0 = lrow[lane];
        float v1 = (lane + 64 < N_CLS) ? lrow[lane + 64] : -INFINITY;
        float m = fmaxf(v0, v1);
        for (int off = 32; off; off >>= 1) m = fmaxf(m, __shfl_down(m, off));
        m = __shfl(m, 0);
        float e0 = expf(v0 - m);
        float e1 = (lane + 64 < N_CLS) ? expf(v1 - m) : 0.0f;
        float s = e0 + e1;
        for (int off = 32; off; off >>= 1) s += __shfl_down(s, off);
        s = __shfl(s, 0);
        if (lane >= 1)          probT[(size_t)(lane - 1) * N_PROP + n] = e0 / s;
        if (lane + 64 < N_CLS)  probT[(size_t)(lane + 63) * N_PROP + n] = e1 / s;
    }
}

// ---------------- K2: per-class NMS (R4-proven body) -----------------------
__global__ __launch_bounds__(256)
void nms_kernel(const float* __restrict__ probT,
                const float* __restrict__ props,
                const float* __restrict__ reg,
                const int* __restrict__ ihp,
                const int* __restrict__ iwp,
                float* __restrict__ out,
                int* __restrict__ count,
                float* __restrict__ compact,
                int* __restrict__ svRow) {
    const int c = blockIdx.x;     // 0..79
    const int t = threadIdx.x;    // 0..255
    const int lane = t & 63;
    const int cls = c + 1;
    const unsigned long long lm = (1ull << lane) - 1ull;

    __shared__ float sSc[N_PROP];
    __shared__ int   sIdx[N_PROP];
    __shared__ int   sPos[N_PROP];
    __shared__ float sx1[N_PROP], sy1[N_PROP], sx2[N_PROP], sy2[N_PROP];
    __shared__ float sar[N_PROP], sSc2[N_PROP];
    __shared__ int   sJdx[N_PROP];
    __shared__ unsigned char sKeep[N_PROP];
    __shared__ int   shV;

    for (int j = t; j < N_PROP; j += 256) sSc[j] = probT[(size_t)c * N_PROP + j];
    __syncthreads();

    // wave-0 ballot compaction (in place; reads of a chunk precede its writes)
    if (t < 64) {
        int V = 0;
        #pragma unroll
        for (int it = 0; it < 16; ++it) {
            int j = it * 64 + lane;
            float sc = (j < N_PROP) ? sSc[j] : -1.0f;
            bool val = (j < N_PROP) && (sc > SCORE_THRESH);
            unsigned long long mask = __ballot(val);
            if (val) { int p = V + __popcll(mask & lm); sSc[p] = sc; sIdx[p] = j; }
            V += __popcll(mask);
        }
        if (lane == 0) shV = V;
    }
    __syncthreads();
    const int V = shV;

    // stable descending rank (ties -> lower original index)
    for (int v = t; v < V; v += 256) {
        float s = sSc[v];
        int id = sIdx[v];
        int r = 0;
        for (int u = 0; u < V; ++u) {
            float su = sSc[u];
            r += (su > s) || (su == s && sIdx[u] < id);
        }
        sPos[v] = r;
    }
    __syncthreads();

    // gather into sorted slots + decode boxes (valid entries only)
    const float W1 = (float)iwp[0] - 1.0f;
    const float H1 = (float)ihp[0] - 1.0f;
    for (int v = t; v < V; v += 256) {
        int r = sPos[v];
        int j = sIdx[v];
        float4 pr = *(const float4*)(props + (size_t)j * 4);
        float w  = pr.z - pr.x + 1.0f;
        float h  = pr.w - pr.y + 1.0f;
        float cx = pr.x + 0.5f * w;
        float cy = pr.y + 0.5f * h;
        float4 rr = *(const float4*)(reg + ((size_t)j * N_CLS + cls) * 4);
        float dx = rr.x / 10.0f;
        float dy = rr.y / 10.0f;
        float dw = fminf(rr.z / 5.0f, BBOX_CLIP);
        float dh = fminf(rr.w / 5.0f, BBOX_CLIP);
        float pcx = dx * w + cx;
        float pcy = dy * h + cy;
        float pw = expf(dw) * w;
        float ph = expf(dh) * h;
        float bx1 = pcx - 0.5f * pw;
        float by1 = pcy - 0.5f * ph;
        float bx2 = pcx + 0.5f * pw - 1.0f;
        float by2 = pcy + 0.5f * ph - 1.0f;
        bx1 = fminf(fmaxf(bx1, 0.0f), W1);
        bx2 = fminf(fmaxf(bx2, 0.0f), W1);
        by1 = fminf(fmaxf(by1, 0.0f), H1);
        by2 = fminf(fmaxf(by2, 0.0f), H1);
        sx1[r] = bx1; sy1[r] = by1; sx2[r] = bx2; sy2[r] = by2;
        sar[r] = (bx2 - bx1 + 1.0f) * (by2 - by1 + 1.0f);
        sSc2[r] = sSc[v];
        sJdx[r] = j;
        sKeep[r] = 1;
    }
    __syncthreads();

    // sequential suppression (reference's sorted greedy scan) — R4-proven
    for (int r = 0; r < V; ++r) {
        if (sKeep[r]) {
            const float X1 = sx1[r], Y1 = sy1[r], X2 = sx2[r], Y2 = sy2[r], A = sar[r];
            for (int v = r + 1 + t; v < V; v += 256) {
                if (sKeep[v]) {
                    float iw = fminf(X2, sx2[v]) - fmaxf(X1, sx1[v]) + 1.0f;
                    float ih = fminf(Y2, sy2[v]) - fmaxf(Y1, sy1[v]) + 1.0f;
                    iw = fmaxf(iw, 0.0f);
                    ih = fmaxf(ih, 0.0f);
                    float inter = iw * ih;
                    float iou = inter / (A + sar[v] - inter);
                    if (iou > NMS_THRESH) sKeep[v] = 0;   // NaN-safe, like ref
                }
            }
        }
        __syncthreads();
    }

    // kept-box writes + wave-aggregated survivor append
    for (int vb = 0; vb < V; vb += 256) {
        int v = vb + t;
        bool k = (v < V) && sKeep[v];
        unsigned long long mask = __ballot(k);
        int cntw = __popcll(mask);
        int base = 0;
        if (lane == 0 && cntw > 0) base = atomicAdd(count, cntw);
        base = __shfl(base, 0);
        if (k) {
            int row = c * N_PROP + sJdx[v];
            size_t o = (size_t)row * 5;
            out[o + 0] = sx1[v];
            out[o + 1] = sy1[v];
            out[o + 2] = sx2[v];
            out[o + 3] = sy2[v];
            out[o + 4] = sSc2[v];
            out[LBL_OFF + row] = (float)cls;
            out[FIN_OFF + row] = 1.0f;
            int pos = base + __popcll(mask & lm);
            compact[pos] = sSc2[v];
            svRow[pos] = row;
        }
    }
}

// ---------------- K3: image threshold + fixup (wave-0 search) --------------
__global__ __launch_bounds__(256)
void finalize_kernel(float* __restrict__ out,
                     const float* __restrict__ compact,
                     const int* __restrict__ svRow,
                     const int* __restrict__ count) {
    __shared__ float lsc[8192];
    __shared__ float sTh;
    const int n = *count;
    const int t = threadIdx.x;
    const int lane = t & 63;

    if (n <= DET_PER_IMG) return;   // th = 0 -> all survivors pass (scores > 0.05)

    const bool useL = (n <= 8192);
    if (useL) {
        for (int i = t; i < n; i += 256) lsc[i] = compact[i];
    }
    __syncthreads();

    // wave-0-only bit-pattern binary search: no block barriers in the loop
    if (t < 64) {
        unsigned lo = 0x3D4CCCCCu, hi = 0x40000000u;  // scores in (0.05, 1.0]
        while (hi - lo > 1u) {
            unsigned mid = lo + ((hi - lo) >> 1);
            float mv = __uint_as_float(mid);
            int cnt = 0;
            if (useL) {
                for (int i = lane; i < n; i += 64) cnt += (lsc[i] >= mv) ? 1 : 0;
            } else {
                for (int i = lane; i < n; i += 64) cnt += (compact[i] >= mv) ? 1 : 0;
            }
            for (int off = 32; off; off >>= 1) cnt += __shfl_xor(cnt, off);
            if (cnt >= DET_PER_IMG + 1) lo = mid; else hi = mid;   // wave-uniform
        }
        if (lane == 0) sTh = __uint_as_float(lo);
    }
    __syncthreads();
    const float th = sTh;

    // fixup: zero rows whose score fails the image threshold
    for (int i = blockIdx.x * 256 + t; i < n; i += gridDim.x * 256) {
        float sc = compact[i];
        if (sc < th) {
            int row = svRow[i];
            size_t o = (size_t)row * 5;
            out[o + 0] = 0.0f;
            out[o + 1] = 0.0f;
            out[o + 2] = 0.0f;
            out[o + 3] = 0.0f;
            out[o + 4] = 0.0f;
            out[LBL_OFF + row] = 0.0f;
            out[FIN_OFF + row] = 0.0f;
        }
    }
}

extern "C" void kernel_launch(void* const* d_in, const int* in_sizes, int n_in,
                              void* d_out, int out_size, void* d_ws, size_t ws_size,
                              hipStream_t stream) {
    const float* logits = (const float*)d_in[0];
    const float* reg    = (const float*)d_in[1];
    const float* props  = (const float*)d_in[2];
    const int*   ihp    = (const int*)d_in[3];
    const int*   iwp    = (const int*)d_in[4];
    float* out = (float*)d_out;

    char* ws = (char*)d_ws;
    int*   count   = (int*)(ws + 0);
    float* probT   = (float*)(ws + 64);
    float* compact = (float*)(ws + 320064);
    int*   svRow   = (int*)(ws + 640064);

    softmax_zero_kernel<<<250, 256, 0, stream>>>(logits, out, count, probT);
    nms_kernel<<<N_FG, 256, 0, stream>>>(probT, props, reg, ihp, iwp,
                                         out, count, compact, svRow);
    finalize_kernel<<<16, 256, 0, stream>>>(out, compact, svRow, count);
}

// Round 12
// 66.692 us; speedup vs baseline: 1.7027x; 1.0538x over previous
//
#include <hip/hip_runtime.h>
#include <math.h>

#define N_PROP 1000
#define N_CLS  81
#define N_FG   80
#define SCORE_THRESH 0.05f
#define NMS_THRESH   0.5f
#define DET_PER_IMG  100
#define BBOX_CLIP    4.135166556742356f   // ln(1000/16)

// d_out layout (560000 floats):
//   [0, 400000)        out5: (80*1000, 5)
//   [400000, 480000)   labels as float
//   [480000, 560000)   final mask as 0.0/1.0
#define LBL_OFF    400000
#define FIN_OFF    480000

// ws layout (bytes):
//   [0,4)               int   survivor count
//   [64, 320064)        float probT[80][1000]
//   [320064, 640064)    float compact survivor scores
//   [640064, 960064)    int   survivor row ids (c*1000+j)

// ---------------- K1: zero output + softmax -> probT (R4-proven) ----------
__global__ __launch_bounds__(256)
void softmax_zero_kernel(const float* __restrict__ logits,
                         float* __restrict__ out,
                         int* __restrict__ count,
                         float* __restrict__ probT) {
    const int b = blockIdx.x;
    const int t = threadIdx.x;
    const int lane = t & 63;
    const int wave = t >> 6;
    if (b == 0 && t == 0) *count = 0;

    float4 z = make_float4(0.f, 0.f, 0.f, 0.f);
    float4* o4 = (float4*)out;
    for (int i = b * 256 + t; i < 140000; i += 250 * 256) o4[i] = z;

    const int n = b * 4 + wave;           // 250 blocks * 4 waves = 1000
    if (n < N_PROP) {
        const float* lrow = logits + (size_t)n * N_CLS;
        float v0 = lrow[lane];
        float v1 = (lane + 64 < N_CLS) ? lrow[lane + 64] : -INFINITY;
        float m = fmaxf(v0, v1);
        for (int off = 32; off; off >>= 1) m = fmaxf(m, __shfl_down(m, off));
        m = __shfl(m, 0);
        float e0 = expf(v0 - m);
        float e1 = (lane + 64 < N_CLS) ? expf(v1 - m) : 0.0f;
        float s = e0 + e1;
        for (int off = 32; off; off >>= 1) s += __shfl_down(s, off);
        s = __shfl(s, 0);
        if (lane >= 1)          probT[(size_t)(lane - 1) * N_PROP + n] = e0 / s;
        if (lane + 64 < N_CLS)  probT[(size_t)(lane + 63) * N_PROP + n] = e1 / s;
    }
}

// ---------------- K2: per-class NMS, bitmask suppression --------------------
__global__ __launch_bounds__(256)
void nms_kernel(const float* __restrict__ probT,
                const float* __restrict__ props,
                const float* __restrict__ reg,
                const int* __restrict__ ihp,
                const int* __restrict__ iwp,
                float* __restrict__ out,
                int* __restrict__ count,
                float* __restrict__ compact,
                int* __restrict__ svRow) {
    const int c = blockIdx.x;     // 0..79
    const int t = threadIdx.x;    // 0..255
    const int lane = t & 63;
    const int cls = c + 1;
    const unsigned long long lm = (1ull << lane) - 1ull;

    __shared__ float sSc[N_PROP];
    __shared__ int   sIdx[N_PROP];
    __shared__ int   sPos[N_PROP];
    __shared__ float sx1[N_PROP], sy1[N_PROP], sx2[N_PROP], sy2[N_PROP];
    __shared__ float sar[N_PROP], sSc2[N_PROP];
    __shared__ int   sJdx[N_PROP];
    __shared__ unsigned char sKeep[N_PROP];
    __shared__ unsigned long long sColMask[128][2];   // rows suppressing column t
    __shared__ int   shV;

    for (int j = t; j < N_PROP; j += 256) sSc[j] = probT[(size_t)c * N_PROP + j];
    __syncthreads();

    // wave-0 ballot compaction (in place; reads of a chunk precede its writes)
    if (t < 64) {
        int V = 0;
        #pragma unroll
        for (int it = 0; it < 16; ++it) {
            int j = it * 64 + lane;
            float sc = (j < N_PROP) ? sSc[j] : -1.0f;
            bool val = (j < N_PROP) && (sc > SCORE_THRESH);
            unsigned long long mask = __ballot(val);
            if (val) { int p = V + __popcll(mask & lm); sSc[p] = sc; sIdx[p] = j; }
            V += __popcll(mask);
        }
        if (lane == 0) shV = V;
    }
    __syncthreads();
    const int V = shV;

    const float W1 = (float)iwp[0] - 1.0f;
    const float H1 = (float)ihp[0] - 1.0f;

    if (V <= 128) {
        // ---- rank + decode: thread t owns compacted entry t ----
        if (t < V) {
            float s = sSc[t];
            int id = sIdx[t];
            int r = 0;
            for (int u = 0; u < V; ++u) {
                float su = sSc[u];
                r += (su > s) || (su == s && sIdx[u] < id);
            }
            float4 pr = *(const float4*)(props + (size_t)id * 4);
            float w  = pr.z - pr.x + 1.0f;
            float h  = pr.w - pr.y + 1.0f;
            float cx = pr.x + 0.5f * w;
            float cy = pr.y + 0.5f * h;
            float4 rr = *(const float4*)(reg + ((size_t)id * N_CLS + cls) * 4);
            float dx = rr.x / 10.0f;
            float dy = rr.y / 10.0f;
            float dw = fminf(rr.z / 5.0f, BBOX_CLIP);
            float dh = fminf(rr.w / 5.0f, BBOX_CLIP);
            float pcx = dx * w + cx;
            float pcy = dy * h + cy;
            float pw = expf(dw) * w;
            float ph = expf(dh) * h;
            float bx1 = fminf(fmaxf(pcx - 0.5f * pw, 0.0f), W1);
            float by1 = fminf(fmaxf(pcy - 0.5f * ph, 0.0f), H1);
            float bx2 = fminf(fmaxf(pcx + 0.5f * pw - 1.0f, 0.0f), W1);
            float by2 = fminf(fmaxf(pcy + 0.5f * ph - 1.0f, 0.0f), H1);
            sx1[r] = bx1; sy1[r] = by1; sx2[r] = bx2; sy2[r] = by2;
            sar[r] = (bx2 - bx1 + 1.0f) * (by2 - by1 + 1.0f);
            sSc2[r] = s;
            sJdx[r] = id;
        }
        __syncthreads();

        // ---- column suppressor masks: thread t owns sorted column t ----
        if (t < V) {
            const float X1 = sx1[t], Y1 = sy1[t], X2 = sx2[t], Y2 = sy2[t], A = sar[t];
            unsigned long long m0 = 0ull, m1 = 0ull;
            for (int r = 0; r < t; ++r) {
                float iw = fmaxf(fminf(sx2[r], X2) - fmaxf(sx1[r], X1) + 1.0f, 0.0f);
                float ih = fmaxf(fminf(sy2[r], Y2) - fmaxf(sy1[r], Y1) + 1.0f, 0.0f);
                float inter = iw * ih;
                float iou = inter / (sar[r] + A - inter);
                if (iou > NMS_THRESH) {            // NaN-safe, like ref
                    if (r < 64) m0 |= 1ull << r; else m1 |= 1ull << (r - 64);
                }
            }
            sColMask[t][0] = m0;
            sColMask[t][1] = m1;
        }
        __syncthreads();

        // ---- wave 0: register/ballot greedy scan + writes (R10-proven) ----
        if (t < 64) {
            const bool hasA = (lane < V), hasB = (64 + lane < V);
            unsigned long long Mlo = 0ull, M2lo = 0ull, M2hi = 0ull;
            if (hasA) Mlo  = sColMask[lane][0];
            if (hasB) { M2lo = sColMask[64 + lane][0]; M2hi = sColMask[64 + lane][1]; }

            unsigned long long keep = 0ull, keep2 = 0ull;
            bool a = hasA, a2 = hasB;   // undecided flags
            while (true) {
                unsigned long long b1 = __ballot(a);
                unsigned long long b2 = __ballot(a2);
                if (!(b1 | b2)) break;
                int r = b1 ? (__ffsll((long long)b1) - 1) : (64 + __ffsll((long long)b2) - 1);
                if (r < 64) {
                    keep |= 1ull << r;
                    if (a  && ((Mlo  >> r) & 1ull)) a  = false;
                    if (a2 && ((M2lo >> r) & 1ull)) a2 = false;
                    if (lane == r) a = false;
                } else {
                    int rr = r - 64;
                    keep2 |= 1ull << rr;
                    if (a2 && ((M2hi >> rr) & 1ull)) a2 = false;
                    if (lane == rr) a2 = false;
                }
            }

            int total = __popcll(keep) + __popcll(keep2);
            int base = 0;
            if (lane == 0 && total > 0) base = atomicAdd(count, total);
            base = __shfl(base, 0);
            if ((keep >> lane) & 1ull) {
                float sc = sSc2[lane];
                int row = c * N_PROP + sJdx[lane];
                size_t o = (size_t)row * 5;
                out[o + 0] = sx1[lane]; out[o + 1] = sy1[lane];
                out[o + 2] = sx2[lane]; out[o + 3] = sy2[lane];
                out[o + 4] = sc;
                out[LBL_OFF + row] = (float)cls;
                out[FIN_OFF + row] = 1.0f;
                int pos = base + __popcll(keep & lm);
                compact[pos] = sc; svRow[pos] = row;
            }
            if ((keep2 >> lane) & 1ull) {
                float sc = sSc2[64 + lane];
                int row = c * N_PROP + sJdx[64 + lane];
                size_t o = (size_t)row * 5;
                out[o + 0] = sx1[64 + lane]; out[o + 1] = sy1[64 + lane];
                out[o + 2] = sx2[64 + lane]; out[o + 3] = sy2[64 + lane];
                out[o + 4] = sc;
                out[LBL_OFF + row] = (float)cls;
                out[FIN_OFF + row] = 1.0f;
                int pos = base + __popcll(keep) + __popcll(keep2 & lm);
                compact[pos] = sc; svRow[pos] = row;
            }
        }
    } else {
        // ---- fallback V > 128: R11-proven sequential path ----
        for (int v = t; v < V; v += 256) {
            float s = sSc[v];
            int id = sIdx[v];
            int r = 0;
            for (int u = 0; u < V; ++u) {
                float su = sSc[u];
                r += (su > s) || (su == s && sIdx[u] < id);
            }
            sPos[v] = r;
        }
        __syncthreads();
        for (int v = t; v < V; v += 256) {
            int r = sPos[v];
            int j = sIdx[v];
            float4 pr = *(const float4*)(props + (size_t)j * 4);
            float w  = pr.z - pr.x + 1.0f;
            float h  = pr.w - pr.y + 1.0f;
            float cx = pr.x + 0.5f * w;
            float cy = pr.y + 0.5f * h;
            float4 rr = *(const float4*)(reg + ((size_t)j * N_CLS + cls) * 4);
            float dx = rr.x / 10.0f;
            float dy = rr.y / 10.0f;
            float dw = fminf(rr.z / 5.0f, BBOX_CLIP);
            float dh = fminf(rr.w / 5.0f, BBOX_CLIP);
            float pcx = dx * w + cx;
            float pcy = dy * h + cy;
            float pw = expf(dw) * w;
            float ph = expf(dh) * h;
            float bx1 = fminf(fmaxf(pcx - 0.5f * pw, 0.0f), W1);
            float by1 = fminf(fmaxf(pcy - 0.5f * ph, 0.0f), H1);
            float bx2 = fminf(fmaxf(pcx + 0.5f * pw - 1.0f, 0.0f), W1);
            float by2 = fminf(fmaxf(pcy + 0.5f * ph - 1.0f, 0.0f), H1);
            sx1[r] = bx1; sy1[r] = by1; sx2[r] = bx2; sy2[r] = by2;
            sar[r] = (bx2 - bx1 + 1.0f) * (by2 - by1 + 1.0f);
            sSc2[r] = sSc[v];
            sJdx[r] = j;
            sKeep[r] = 1;
        }
        __syncthreads();
        for (int r = 0; r < V; ++r) {
            if (sKeep[r]) {
                const float X1 = sx1[r], Y1 = sy1[r], X2 = sx2[r], Y2 = sy2[r], A = sar[r];
                for (int v = r + 1 + t; v < V; v += 256) {
                    if (sKeep[v]) {
                        float iw = fmaxf(fminf(X2, sx2[v]) - fmaxf(X1, sx1[v]) + 1.0f, 0.0f);
                        float ih = fmaxf(fminf(Y2, sy2[v]) - fmaxf(Y1, sy1[v]) + 1.0f, 0.0f);
                        float inter = iw * ih;
                        float iou = inter / (A + sar[v] - inter);
                        if (iou > NMS_THRESH) sKeep[v] = 0;
                    }
                }
            }
            __syncthreads();
        }
        for (int vb = 0; vb < V; vb += 256) {
            int v = vb + t;
            bool k = (v < V) && sKeep[v];
            unsigned long long mask = __ballot(k);
            int cntw = __popcll(mask);
            int base = 0;
            if (lane == 0 && cntw > 0) base = atomicAdd(count, cntw);
            base = __shfl(base, 0);
            if (k) {
                int row = c * N_PROP + sJdx[v];
                size_t o = (size_t)row * 5;
                out[o + 0] = sx1[v]; out[o + 1] = sy1[v];
                out[o + 2] = sx2[v]; out[o + 3] = sy2[v];
                out[o + 4] = sSc2[v];
                out[LBL_OFF + row] = (float)cls;
                out[FIN_OFF + row] = 1.0f;
                int pos = base + __popcll(mask & lm);
                compact[pos] = sSc2[v];
                svRow[pos] = row;
            }
        }
    }
}

// ---------------- K3: image threshold + fixup (R11-proven) -----------------
__global__ __launch_bounds__(256)
void finalize_kernel(float* __restrict__ out,
                     const float* __restrict__ compact,
                     const int* __restrict__ svRow,
                     const int* __restrict__ count) {
    __shared__ float lsc[8192];
    __shared__ float sTh;
    const int n = *count;
    const int t = threadIdx.x;
    const int lane = t & 63;

    if (n <= DET_PER_IMG) return;   // th = 0 -> all survivors pass (scores > 0.05)

    const bool useL = (n <= 8192);
    if (useL) {
        for (int i = t; i < n; i += 256) lsc[i] = compact[i];
    }
    __syncthreads();

    // wave-0-only bit-pattern binary search: no block barriers in the loop
    if (t < 64) {
        unsigned lo = 0x3D4CCCCCu, hi = 0x40000000u;  // scores in (0.05, 1.0]
        while (hi - lo > 1u) {
            unsigned mid = lo + ((hi - lo) >> 1);
            float mv = __uint_as_float(mid);
            int cnt = 0;
            if (useL) {
                for (int i = lane; i < n; i += 64) cnt += (lsc[i] >= mv) ? 1 : 0;
            } else {
                for (int i = lane; i < n; i += 64) cnt += (compact[i] >= mv) ? 1 : 0;
            }
            for (int off = 32; off; off >>= 1) cnt += __shfl_xor(cnt, off);
            if (cnt >= DET_PER_IMG + 1) lo = mid; else hi = mid;   // wave-uniform
        }
        if (lane == 0) sTh = __uint_as_float(lo);
    }
    __syncthreads();
    const float th = sTh;

    // fixup: zero rows whose score fails the image threshold
    for (int i = blockIdx.x * 256 + t; i < n; i += gridDim.x * 256) {
        float sc = compact[i];
        if (sc < th) {
            int row = svRow[i];
            size_t o = (size_t)row * 5;
            out[o + 0] = 0.0f;
            out[o + 1] = 0.0f;
            out[o + 2] = 0.0f;
            out[o + 3] = 0.0f;
            out[o + 4] = 0.0f;
            out[LBL_OFF + row] = 0.0f;
            out[FIN_OFF + row] = 0.0f;
        }
    }
}

extern "C" void kernel_launch(void* const* d_in, const int* in_sizes, int n_in,
                              void* d_out, int out_size, void* d_ws, size_t ws_size,
                              hipStream_t stream) {
    const float* logits = (const float*)d_in[0];
    const float* reg    = (const float*)d_in[1];
    const float* props  = (const float*)d_in[2];
    const int*   ihp    = (const int*)d_in[3];
    const int*   iwp    = (const int*)d_in[4];
    float* out = (float*)d_out;

    char* ws = (char*)d_ws;
    int*   count   = (int*)(ws + 0);
    float* probT   = (float*)(ws + 64);
    float* compact = (float*)(ws + 320064);
    int*   svRow   = (int*)(ws + 640064);

    softmax_zero_kernel<<<250, 256, 0, stream>>>(logits, out, count, probT);
    nms_kernel<<<N_FG, 256, 0, stream>>>(probT, props, reg, ihp, iwp,
                                         out, count, compact, svRow);
    finalize_kernel<<<16, 256, 0, stream>>>(out, compact, svRow, count);
}